// Round 6
// baseline (617.328 us; speedup 1.0000x reference)
//
#include <hip/hip_runtime.h>
#include <hip/hip_fp16.h>
#include <math.h>

typedef float4 f4;
#define NEG_SLOPE 0.2f

union h4pack { float2 f; __half2 h[2]; };

// ---- M[d][h] = sum_c We[d, h*C+c] * ae[h, c]   (M1: 16x4 from We1/ae1, M2 from We2/ae2)
__global__ void k_prep(const float* __restrict__ We1, const float* __restrict__ ae1,
                       const float* __restrict__ We2, const float* __restrict__ ae2,
                       float* __restrict__ M) {
    int t = threadIdx.x;                  // 128 threads
    if (t >= 128) return;
    int sel = t >> 6, i = t & 63, d = i >> 2, h = i & 3;
    const float* W  = sel ? We2 : We1;
    const float* ae = sel ? ae2 : ae1;
    int C = sel ? 8 : 32, ncol = sel ? 32 : 128;
    float s = 0.f;
    for (int c = 0; c < C; ++c) s += W[d * ncol + h * C + c] * ae[h * C + c];
    M[sel * 64 + d * 4 + h] = s;
}

// ---- deg[dst]++ per real edge (int atomics only)
__global__ void k_deg(const int* __restrict__ ei, int* __restrict__ deg, int E) {
    int e = blockIdx.x * 256 + threadIdx.x;
    if (e < E) atomicAdd(&deg[ei[E + e]], 1);
}

// ---- exclusive scan of deg -> offsets[0..N], cursor copy. One block of 1024.
__global__ void k_scan(const int* __restrict__ deg, int* __restrict__ offsets,
                       int* __restrict__ cursor, int N) {
    __shared__ int ts[1024];
    int t = threadIdx.x;
    int CH = (N + 1023) / 1024;
    int lo = t * CH, hi = min(lo + CH, N);
    int s = 0;
    for (int i = lo; i < hi; ++i) s += deg[i];
    ts[t] = s;
    __syncthreads();
    for (int off = 1; off < 1024; off <<= 1) {
        int v = (t >= off) ? ts[t - off] : 0;
        __syncthreads();
        ts[t] += v;
        __syncthreads();
    }
    int run = (t == 0) ? 0 : ts[t - 1];
    for (int i = lo; i < hi; ++i) { offsets[i] = run; cursor[i] = run; run += deg[i]; }
    if (t == 1023) offsets[N] = ts[1023];
}

// ---- EDGE-ORDER ale for both layers: pure streaming, no scatter, no atomics
__global__ void k_ale_lin(const float* __restrict__ ea, const float* __restrict__ Mbuf,
                          __half* __restrict__ ale1_e, __half* __restrict__ ale2_e, int E) {
    __shared__ float Ms[128];
    if (threadIdx.x < 128) Ms[threadIdx.x] = Mbuf[threadIdx.x];
    __syncthreads();
    int e = blockIdx.x * 256 + threadIdx.x;
    if (e >= E) return;
    const f4* row = (const f4*)(ea + (size_t)e * 16);
    f4 r0 = row[0], r1 = row[1], r2 = row[2], r3 = row[3];
    float a[16] = { r0.x, r0.y, r0.z, r0.w, r1.x, r1.y, r1.z, r1.w,
                    r2.x, r2.y, r2.z, r2.w, r3.x, r3.y, r3.z, r3.w };
    float s10 = 0.f, s11 = 0.f, s12 = 0.f, s13 = 0.f;
    float s20 = 0.f, s21 = 0.f, s22 = 0.f, s23 = 0.f;
#pragma unroll
    for (int dd = 0; dd < 16; ++dd) {
        float av = a[dd];
        s10 += av * Ms[dd * 4 + 0]; s11 += av * Ms[dd * 4 + 1];
        s12 += av * Ms[dd * 4 + 2]; s13 += av * Ms[dd * 4 + 3];
        s20 += av * Ms[64 + dd * 4 + 0]; s21 += av * Ms[64 + dd * 4 + 1];
        s22 += av * Ms[64 + dd * 4 + 2]; s23 += av * Ms[64 + dd * 4 + 3];
    }
    h4pack p1, p2;
    p1.h[0] = __floats2half2_rn(s10, s11); p1.h[1] = __floats2half2_rn(s12, s13);
    p2.h[0] = __floats2half2_rn(s20, s21); p2.h[1] = __floats2half2_rn(s22, s23);
    ((float2*)ale1_e)[e] = p1.f;
    ((float2*)ale2_e)[e] = p2.f;
}

// ---- fill CSR (by dst): single packed int2{src, eid} scatter per edge
__global__ void k_fill(const int* __restrict__ ei, int* __restrict__ cursor,
                       int2* __restrict__ csr_se, int E) {
    int e = blockIdx.x * 256 + threadIdx.x;
    if (e >= E) return;
    int sr = ei[e], d = ei[E + e];
    int slot = atomicAdd(&cursor[d], 1);
    csr_se[slot] = make_int2(sr, e);
}

// ---- LDS-tiled fp32 GEMM, fp16 output: Hout[N,NOUT] = half(X[N,128] @ W[128,NOUT])
template<int NOUT, int ROWS>
__global__ __launch_bounds__(256) void k_gemm(const float* __restrict__ X,
                                              const float* __restrict__ W,
                                              __half* __restrict__ Hout, int N) {
    __shared__ __align__(16) float xs[ROWS][128];
    int row0 = blockIdx.x * ROWS;
    int tid = threadIdx.x;
    constexpr int NF4 = ROWS * 32;
    const f4* x4 = (const f4*)X;
    for (int i = tid; i < NF4; i += 256) {
        int r = i >> 5, k4 = i & 31;
        f4 v;
        if (row0 + r < N) v = x4[(size_t)(row0 + r) * 32 + k4];
        else { v.x = v.y = v.z = v.w = 0.f; }
        ((f4*)&xs[r][0])[k4] = v;
    }
    __syncthreads();
    constexpr int GRP = 256 / NOUT;
    constexpr int PR  = ROWS / GRP;
    int col = tid % NOUT, rg = tid / NOUT;
    float acc[PR];
#pragma unroll
    for (int r = 0; r < PR; ++r) acc[r] = 0.f;
    for (int k = 0; k < 128; ++k) {
        float w = W[k * NOUT + col];
#pragma unroll
        for (int r = 0; r < PR; ++r) acc[r] += xs[rg + r * GRP][k] * w;
    }
#pragma unroll
    for (int r = 0; r < PR; ++r) {
        int row = row0 + rg + r * GRP;
        if (row < N) Hout[(size_t)row * NOUT + col] = __float2half(acc[r]);
    }
}

// ---- per (node, head): al_src/al_dst from fp16 h
template<int C>
__global__ void k_al(const __half* __restrict__ Hm, const float* __restrict__ as_,
                     const float* __restrict__ ad_, float* __restrict__ als,
                     float* __restrict__ ald, int N) {
    int idx = blockIdx.x * 256 + threadIdx.x;
    int n = idx >> 2, h = idx & 3;
    if (n >= N) return;
    constexpr int CH = C / 4;
    const __half2* h2p = (const __half2*)(Hm + (size_t)n * C + h * CH);
    float a = 0.f, b = 0.f;
#pragma unroll
    for (int c = 0; c < CH / 2; ++c) {
        float2 v = __half22float2(h2p[c]);
        a += v.x * as_[h * CH + 2 * c] + v.y * as_[h * CH + 2 * c + 1];
        b += v.x * ad_[h * CH + 2 * c] + v.y * ad_[h * CH + 2 * c + 1];
    }
    als[n * 4 + h] = a;
    ald[n * 4 + h] = b;
}

// ---- wave-per-node: alpha_csr[s][h] = exp(leaky(als[src]+ald[n]+ale_e[eid][h])),
//      reading ale via eid indirection (random read, L3-resident), writing contiguous.
//      emit rden[n][h] = 1/(sum_exp + e_self + 1e-16), selfa[n][h] = e_self
__global__ __launch_bounds__(256) void k_alpha_node(const __half* __restrict__ ale_e,
                                                    __half* __restrict__ alpha_csr,
                                                    const int2* __restrict__ csr_se,
                                                    const float* __restrict__ als,
                                                    const float* __restrict__ ald,
                                                    const int* __restrict__ offsets,
                                                    float* __restrict__ rden,
                                                    float* __restrict__ selfa, int N) {
    int n = (blockIdx.x * 256 + threadIdx.x) >> 6;
    int lane = threadIdx.x & 63;
    if (n >= N) return;
    int j = lane >> 2, h = lane & 3;   // 16 edges x 4 heads per iteration
    int s0 = offsets[n], s1 = offsets[n + 1];
    float aldn = ald[n * 4 + h];
    float den = 0.f, asum = 0.f;
    for (int base = s0; base < s1; base += 16) {
        int s = base + j;
        if (s < s1) {
            int2 se = csr_se[s];
            float ale = __half2float(ale_e[(size_t)se.y * 4 + h]);
            float v = als[se.x * 4 + h] + aldn + ale;
            v = (v > 0.f) ? v : NEG_SLOPE * v;
            float e = __expf(v);
            alpha_csr[s * 4 + h] = __float2half(e);
            den += e; asum += ale;
        }
    }
    den  += __shfl_xor(den, 4);  den  += __shfl_xor(den, 8);
    den  += __shfl_xor(den, 16); den  += __shfl_xor(den, 32);
    asum += __shfl_xor(asum, 4);  asum += __shfl_xor(asum, 8);
    asum += __shfl_xor(asum, 16); asum += __shfl_xor(asum, 32);
    if (j == 0) {
        float rdeg = 1.f / fmaxf((float)(s1 - s0), 1.f);
        float v = als[n * 4 + h] + aldn + asum * rdeg;
        v = (v > 0.f) ? v : NEG_SLOPE * v;
        float es = __expf(v);
        selfa[n * 4 + h] = es;
        rden[n * 4 + h] = 1.f / (den + es + 1e-16f);
    }
}

// ---- layer-1 aggregation: gather-FMA, wave-per-node, unroll x4, predicated tail
__global__ __launch_bounds__(256) void k_aggf128(const __half* __restrict__ h16,
                                                 const __half* __restrict__ alpha16,
                                                 const float* __restrict__ rden,
                                                 const float* __restrict__ selfa,
                                                 const int* __restrict__ offsets,
                                                 const int2* __restrict__ csr_se,
                                                 const float* __restrict__ bias,
                                                 float* __restrict__ Out, int N) {
    int n = (blockIdx.x * 256 + threadIdx.x) >> 6;
    int lane = threadIdx.x & 63;
    if (n >= N) return;
    int hd = lane >> 4;                 // head of channels 2l, 2l+1
    int s0 = offsets[n], s1 = offsets[n + 1];
    const __half2* H2 = (const __half2*)h16;
    float acc0 = 0.f, acc1 = 0.f;
    int e1 = s1 - 1;
    for (int s = s0; s < s1; s += 4) {
        int sA = s;
        int sB = min(s + 1, e1), sC = min(s + 2, e1), sD = min(s + 3, e1);
        int srcA = csr_se[sA].x, srcB = csr_se[sB].x;
        int srcC = csr_se[sC].x, srcD = csr_se[sD].x;
        float aA = __half2float(alpha16[sA * 4 + hd]);
        float aB = (s + 1 <= e1) ? __half2float(alpha16[sB * 4 + hd]) : 0.f;
        float aC = (s + 2 <= e1) ? __half2float(alpha16[sC * 4 + hd]) : 0.f;
        float aD = (s + 3 <= e1) ? __half2float(alpha16[sD * 4 + hd]) : 0.f;
        __half2 hA = H2[(size_t)srcA * 64 + lane];
        __half2 hB = H2[(size_t)srcB * 64 + lane];
        __half2 hC = H2[(size_t)srcC * 64 + lane];
        __half2 hD = H2[(size_t)srcD * 64 + lane];
        float2 fA = __half22float2(hA), fB = __half22float2(hB);
        float2 fC = __half22float2(hC), fD = __half22float2(hD);
        acc0 = fmaf(aA, fA.x, acc0); acc1 = fmaf(aA, fA.y, acc1);
        acc0 = fmaf(aB, fB.x, acc0); acc1 = fmaf(aB, fB.y, acc1);
        acc0 = fmaf(aC, fC.x, acc0); acc1 = fmaf(aC, fC.y, acc1);
        acc0 = fmaf(aD, fD.x, acc0); acc1 = fmaf(aD, fD.y, acc1);
    }
    float sa = selfa[n * 4 + hd];
    float2 hn = __half22float2(H2[(size_t)n * 64 + lane]);
    acc0 = fmaf(sa, hn.x, acc0);
    acc1 = fmaf(sa, hn.y, acc1);
    float rd = rden[n * 4 + hd];
    float2 bv = ((const float2*)bias)[lane];
    float2 o;
    o.x = fmaxf(fmaf(acc0, rd, bv.x), 0.f);
    o.y = fmaxf(fmaf(acc1, rd, bv.y), 0.f);
    ((float2*)Out)[(size_t)n * 64 + lane] = o;
}

// ---- layer-2 aggregation: 4 edges/iter across the wave, unroll x2 (8 gathers in flight)
__global__ __launch_bounds__(256) void k_aggf32(const __half* __restrict__ h16,
                                                const __half* __restrict__ alpha16,
                                                const float* __restrict__ rden,
                                                const float* __restrict__ selfa,
                                                const int* __restrict__ offsets,
                                                const int2* __restrict__ csr_se,
                                                const float* __restrict__ bias,
                                                float* __restrict__ Out, int N) {
    int n = (blockIdx.x * 256 + threadIdx.x) >> 6;
    int lane = threadIdx.x & 63;
    if (n >= N) return;
    int j = lane >> 4;                  // edge sub-slot 0..3
    int p = lane & 15;                  // half2 index -> channels 2p,2p+1
    int hd = p >> 2;                    // head
    int s0 = offsets[n], s1 = offsets[n + 1];
    const __half2* H2 = (const __half2*)h16;
    float acc0 = 0.f, acc1 = 0.f;
    int e1 = s1 - 1;
    for (int s = s0 + j; s < s1; s += 8) {
        int sA = s;
        int sB = min(s + 4, e1);
        int srcA = csr_se[sA].x, srcB = csr_se[sB].x;
        float aA = __half2float(alpha16[sA * 4 + hd]);
        float aB = (s + 4 <= e1) ? __half2float(alpha16[sB * 4 + hd]) : 0.f;
        __half2 hA = H2[(size_t)srcA * 16 + p];
        __half2 hB = H2[(size_t)srcB * 16 + p];
        float2 fA = __half22float2(hA), fB = __half22float2(hB);
        acc0 = fmaf(aA, fA.x, acc0); acc1 = fmaf(aA, fA.y, acc1);
        acc0 = fmaf(aB, fB.x, acc0); acc1 = fmaf(aB, fB.y, acc1);
    }
    acc0 += __shfl_xor(acc0, 16); acc0 += __shfl_xor(acc0, 32);
    acc1 += __shfl_xor(acc1, 16); acc1 += __shfl_xor(acc1, 32);
    if (j == 0) {
        float sa = selfa[n * 4 + hd];
        float2 hn = __half22float2(H2[(size_t)n * 16 + p]);
        acc0 = fmaf(sa, hn.x, acc0);
        acc1 = fmaf(sa, hn.y, acc1);
        float rd = rden[n * 4 + hd];
        float2 bv = ((const float2*)bias)[p];
        float2 o;
        o.x = fmaxf(fmaf(acc0, rd, bv.x), 0.f);
        o.y = fmaxf(fmaf(acc1, rd, bv.y), 0.f);
        ((float2*)Out)[(size_t)n * 16 + p] = o;
    }
}

// ---- group boundaries: gstart[g] = lower_bound(batch, g), g in [0,64]
__global__ void k_gbound(const int* __restrict__ batch, int* __restrict__ gstart, int N, int G) {
    int g = threadIdx.x;
    if (g > G) return;
    int lo = 0, hi = N;
    while (lo < hi) {
        int mid = (lo + hi) >> 1;
        if (batch[mid] < g) lo = mid + 1; else hi = mid;
    }
    gstart[g] = lo;
}

// ---- atomic-free mean pool: one block per group, contiguous slab reduce
__global__ __launch_bounds__(256) void k_pool_grp(const float* __restrict__ out2,
                                                  const int* __restrict__ gstart,
                                                  float* __restrict__ pooled, int G) {
    __shared__ float red[8][32];
    int g = blockIdx.x;
    int t = threadIdx.x, c = t & 31, r = t >> 5;   // r in 0..7
    int s0 = gstart[g], s1 = gstart[g + 1];
    float acc = 0.f;
    for (int n = s0 + r; n < s1; n += 8) acc += out2[(size_t)n * 32 + c];
    red[r][c] = acc;
    __syncthreads();
    if (r == 0) {
        float s = red[0][c];
#pragma unroll
        for (int i = 1; i < 8; ++i) s += red[i][c];
        pooled[g * 32 + c] = s;
    }
}

// ---- final: out[g,cls] = (pooled[g]/cnt[g]) @ Wfc + bfc   (cnt from gstart diffs)
__global__ void k_final(const float* __restrict__ pooled, const int* __restrict__ gstart,
                        const float* __restrict__ Wfc, const float* __restrict__ bfc,
                        float* __restrict__ out) {
    int t = threadIdx.x;
    if (t >= 640) return;
    int g = t / 10, cls = t % 10;
    float rc = 1.f / fmaxf((float)(gstart[g + 1] - gstart[g]), 1.f);
    float acc = bfc[cls];
    for (int c = 0; c < 32; ++c) acc += pooled[g * 32 + c] * rc * Wfc[c * 10 + cls];
    out[g * 10 + cls] = acc;
}

extern "C" void kernel_launch(void* const* d_in, const int* in_sizes, int n_in,
                              void* d_out, int out_size, void* d_ws, size_t ws_size,
                              hipStream_t stream) {
    const float* x    = (const float*)d_in[0];
    const int*   ei   = (const int*)  d_in[1];
    const float* ea   = (const float*)d_in[2];
    const int*   batch= (const int*)  d_in[3];
    const float* W1   = (const float*)d_in[4];
    const float* as1  = (const float*)d_in[5];
    const float* ad1  = (const float*)d_in[6];
    const float* We1  = (const float*)d_in[7];
    const float* ae1  = (const float*)d_in[8];
    const float* b1   = (const float*)d_in[9];
    const float* W2   = (const float*)d_in[10];
    const float* as2  = (const float*)d_in[11];
    const float* ad2  = (const float*)d_in[12];
    const float* We2  = (const float*)d_in[13];
    const float* ae2  = (const float*)d_in[14];
    const float* b2   = (const float*)d_in[15];
    const float* Wfc  = (const float*)d_in[16];
    const float* bfc  = (const float*)d_in[17];
    float* out = (float*)d_out;

    const int N  = in_sizes[3];       // 50000
    const int E  = in_sizes[1] / 2;   // 1600000
    const int G  = 64;

    char* w = (char*)d_ws;
    size_t off = 0;
    auto alloc = [&](size_t bytes) -> void* {
        void* p = w + off;
        off = (off + bytes + 255) & ~(size_t)255;
        return p;
    };
    int*    deg      = (int*)   alloc((size_t)N * 4);
    int*    offsets  = (int*)   alloc((size_t)(N + 1) * 4);
    int*    cursor   = (int*)   alloc((size_t)N * 4);
    int2*   csr_se   = (int2*)  alloc((size_t)E * 8);
    __half* ale1_e   = (__half*)alloc((size_t)E * 4 * 2);   // edge order
    __half* ale2_e   = (__half*)alloc((size_t)E * 4 * 2);   // edge order
    __half* alpha_csr= (__half*)alloc((size_t)E * 4 * 2);   // csr order (per layer, reused)
    float*  Mbuf     = (float*) alloc(128 * 4);
    __half* h16      = (__half*)alloc((size_t)N * 128 * 2); // h1 fp16; reused as h2
    float*  out1     = (float*) alloc((size_t)N * 128 * 4); // reused as out2
    float*  als      = (float*) alloc((size_t)N * 4 * 4);
    float*  ald      = (float*) alloc((size_t)N * 4 * 4);
    float*  rden     = (float*) alloc((size_t)N * 4 * 4);
    float*  selfa    = (float*) alloc((size_t)N * 4 * 4);
    int*    gstart   = (int*)   alloc((G + 1) * 4);
    float*  pooled   = (float*) alloc(G * 32 * 4);
    float*  out2 = out1;

    const int eb = (E + 255) / 256;
    const int nb4 = (N + 3) / 4;

    hipMemsetAsync(deg, 0, (size_t)N * 4, stream);

    k_prep<<<1, 128, 0, stream>>>(We1, ae1, We2, ae2, Mbuf);
    k_deg<<<eb, 256, 0, stream>>>(ei, deg, E);
    k_scan<<<1, 1024, 0, stream>>>(deg, offsets, cursor, N);
    k_ale_lin<<<eb, 256, 0, stream>>>(ea, Mbuf, ale1_e, ale2_e, E);
    k_fill<<<eb, 256, 0, stream>>>(ei, cursor, csr_se, E);
    k_gbound<<<1, 128, 0, stream>>>(batch, gstart, N, G);

    // ---------- layer 1 ----------
    k_gemm<128, 16><<<(N + 15) / 16, 256, 0, stream>>>(x, W1, h16, N);
    k_al<128><<<(N * 4 + 255) / 256, 256, 0, stream>>>(h16, as1, ad1, als, ald, N);
    k_alpha_node<<<nb4, 256, 0, stream>>>(ale1_e, alpha_csr, csr_se, als, ald, offsets, rden, selfa, N);
    k_aggf128<<<nb4, 256, 0, stream>>>(h16, alpha_csr, rden, selfa, offsets, csr_se, b1, out1, N);

    // ---------- layer 2 ----------
    k_gemm<32, 64><<<(N + 63) / 64, 256, 0, stream>>>(out1, W2, h16, N);
    k_al<32><<<(N * 4 + 255) / 256, 256, 0, stream>>>(h16, as2, ad2, als, ald, N);
    k_alpha_node<<<nb4, 256, 0, stream>>>(ale2_e, alpha_csr, csr_se, als, ald, offsets, rden, selfa, N);
    k_aggf32<<<nb4, 256, 0, stream>>>(h16, alpha_csr, rden, selfa, offsets, csr_se, b2, out2, N);

    // ---------- pool + fc ----------
    k_pool_grp<<<G, 256, 0, stream>>>(out2, gstart, pooled, G);
    k_final<<<1, 640, 0, stream>>>(pooled, gstart, Wfc, bfc, out);
}

// Round 7
// 388.626 us; speedup vs baseline: 1.5885x; 1.5885x over previous
//
#include <hip/hip_runtime.h>
#include <hip/hip_fp16.h>
#include <math.h>

typedef float4 f4;
#define NEG_SLOPE 0.2f
#define NBMAX 1024          // buckets of 64 nodes; supports N <= 65536
#define BIN_CHUNK 8192

union h4pack { float2 f; __half2 h[2]; };

// ---- M[d][h] = sum_c We[d, h*C+c] * ae[h, c]
__global__ void k_prep(const float* __restrict__ We1, const float* __restrict__ ae1,
                       const float* __restrict__ We2, const float* __restrict__ ae2,
                       float* __restrict__ M) {
    int t = threadIdx.x;                  // 128 threads
    if (t >= 128) return;
    int sel = t >> 6, i = t & 63, d = i >> 2, h = i & 3;
    const float* W  = sel ? We2 : We1;
    const float* ae = sel ? ae2 : ae1;
    int C = sel ? 8 : 32, ncol = sel ? 32 : 128;
    float s = 0.f;
    for (int c = 0; c < C; ++c) s += W[d * ncol + h * C + c] * ae[h * C + c];
    M[sel * 64 + d * 4 + h] = s;
}

// ---- per-block LDS histogram of dst>>6 -> global bucket counts (few atomics)
__global__ __launch_bounds__(256) void k_bhist(const int* __restrict__ ei,
                                               int* __restrict__ bcnt, int E, int NB) {
    __shared__ int hist[NBMAX];
    for (int i = threadIdx.x; i < NB; i += 256) hist[i] = 0;
    __syncthreads();
    int stride = gridDim.x * 256;
    for (int e = blockIdx.x * 256 + threadIdx.x; e < E; e += stride)
        atomicAdd(&hist[ei[E + e] >> 6], 1);
    __syncthreads();
    for (int i = threadIdx.x; i < NB; i += 256) {
        int h = hist[i];
        if (h) atomicAdd(&bcnt[i], h);
    }
}

// ---- exclusive scan of bucket counts -> bprefix[0..NB], bcursor init
__global__ void k_bscan(const int* __restrict__ bcnt, int* __restrict__ bprefix,
                        int* __restrict__ bcursor, int NB) {
    __shared__ int ts[NBMAX];
    int t = threadIdx.x;                 // 1024 threads
    ts[t] = (t < NB) ? bcnt[t] : 0;
    __syncthreads();
    for (int off = 1; off < 1024; off <<= 1) {
        int v = (t >= off) ? ts[t - off] : 0;
        __syncthreads();
        ts[t] += v;
        __syncthreads();
    }
    int excl = (t == 0) ? 0 : ts[t - 1];
    if (t <= NB) {
        bprefix[t] = excl;
        if (t < NB) bcursor[t] = excl;
    }
}

// ---- bin edges by dst-bucket: block-local histogram + one reservation per (block,bucket)
//      record: {src, (dst&63)<<26 | eid}   (eid < 2^26)
__global__ __launch_bounds__(256) void k_bin(const int* __restrict__ ei,
                                             int* __restrict__ bcursor,
                                             int2* __restrict__ binned, int E, int NB) {
    __shared__ int hist[NBMAX], base[NBMAX], cur[NBMAX];
    for (int i = threadIdx.x; i < NB; i += 256) { hist[i] = 0; cur[i] = 0; }
    __syncthreads();
    int e0 = blockIdx.x * BIN_CHUNK;
    int e1 = min(e0 + BIN_CHUNK, E);
    for (int e = e0 + threadIdx.x; e < e1; e += 256)
        atomicAdd(&hist[ei[E + e] >> 6], 1);
    __syncthreads();
    for (int i = threadIdx.x; i < NB; i += 256) {
        int h = hist[i];
        if (h) base[i] = atomicAdd(&bcursor[i], h);
    }
    __syncthreads();
    for (int e = e0 + threadIdx.x; e < e1; e += 256) {
        int sr = ei[e], d = ei[E + e];
        int b = d >> 6;
        int loc = base[b] + atomicAdd(&cur[b], 1);
        binned[loc] = make_int2(sr, ((d & 63) << 26) | e);
    }
}

// ---- per-bucket: derive offsets (local prefix) and scatter csr_se into L2-resident window
__global__ __launch_bounds__(256) void k_csr(const int2* __restrict__ binned,
                                             const int* __restrict__ bprefix,
                                             int* __restrict__ offsets,
                                             int2* __restrict__ csr_se,
                                             int N, int E, int NB) {
    __shared__ int nhist[64], noff[65];
    int b = blockIdx.x;
    if (threadIdx.x < 64) nhist[threadIdx.x] = 0;
    __syncthreads();
    int lo = bprefix[b], hi = bprefix[b + 1];
    for (int s = lo + threadIdx.x; s < hi; s += 256)
        atomicAdd(&nhist[(binned[s].y >> 26) & 63], 1);
    __syncthreads();
    if (threadIdx.x == 0) {
        int run = 0;
        for (int i = 0; i < 64; ++i) { noff[i] = run; run += nhist[i]; }
        noff[64] = run;
    }
    __syncthreads();
    int nlo = b << 6;
    int nbn = min(64, N - nlo);
    if (threadIdx.x < nbn) offsets[nlo + threadIdx.x] = lo + noff[threadIdx.x];
    if (b == NB - 1 && threadIdx.x == 0) offsets[N] = E;
    if (threadIdx.x < 64) nhist[threadIdx.x] = 0;   // reuse as per-node cursor
    __syncthreads();
    for (int s = lo + threadIdx.x; s < hi; s += 256) {
        int2 r = binned[s];
        int dl = (r.y >> 26) & 63;
        int slot = lo + noff[dl] + atomicAdd(&nhist[dl], 1);
        csr_se[slot] = make_int2(r.x, r.y & 0x03FFFFFF);
    }
}

// ---- EDGE-ORDER ale for both layers: pure streaming
__global__ void k_ale_lin(const float* __restrict__ ea, const float* __restrict__ Mbuf,
                          __half* __restrict__ ale1_e, __half* __restrict__ ale2_e, int E) {
    __shared__ float Ms[128];
    if (threadIdx.x < 128) Ms[threadIdx.x] = Mbuf[threadIdx.x];
    __syncthreads();
    int e = blockIdx.x * 256 + threadIdx.x;
    if (e >= E) return;
    const f4* row = (const f4*)(ea + (size_t)e * 16);
    f4 r0 = row[0], r1 = row[1], r2 = row[2], r3 = row[3];
    float a[16] = { r0.x, r0.y, r0.z, r0.w, r1.x, r1.y, r1.z, r1.w,
                    r2.x, r2.y, r2.z, r2.w, r3.x, r3.y, r3.z, r3.w };
    float s10 = 0.f, s11 = 0.f, s12 = 0.f, s13 = 0.f;
    float s20 = 0.f, s21 = 0.f, s22 = 0.f, s23 = 0.f;
#pragma unroll
    for (int dd = 0; dd < 16; ++dd) {
        float av = a[dd];
        s10 += av * Ms[dd * 4 + 0]; s11 += av * Ms[dd * 4 + 1];
        s12 += av * Ms[dd * 4 + 2]; s13 += av * Ms[dd * 4 + 3];
        s20 += av * Ms[64 + dd * 4 + 0]; s21 += av * Ms[64 + dd * 4 + 1];
        s22 += av * Ms[64 + dd * 4 + 2]; s23 += av * Ms[64 + dd * 4 + 3];
    }
    h4pack p1, p2;
    p1.h[0] = __floats2half2_rn(s10, s11); p1.h[1] = __floats2half2_rn(s12, s13);
    p2.h[0] = __floats2half2_rn(s20, s21); p2.h[1] = __floats2half2_rn(s22, s23);
    ((float2*)ale1_e)[e] = p1.f;
    ((float2*)ale2_e)[e] = p2.f;
}

// ---- LDS-tiled fp32 GEMM, fp16 output
template<int NOUT, int ROWS>
__global__ __launch_bounds__(256) void k_gemm(const float* __restrict__ X,
                                              const float* __restrict__ W,
                                              __half* __restrict__ Hout, int N) {
    __shared__ __align__(16) float xs[ROWS][128];
    int row0 = blockIdx.x * ROWS;
    int tid = threadIdx.x;
    constexpr int NF4 = ROWS * 32;
    const f4* x4 = (const f4*)X;
    for (int i = tid; i < NF4; i += 256) {
        int r = i >> 5, k4 = i & 31;
        f4 v;
        if (row0 + r < N) v = x4[(size_t)(row0 + r) * 32 + k4];
        else { v.x = v.y = v.z = v.w = 0.f; }
        ((f4*)&xs[r][0])[k4] = v;
    }
    __syncthreads();
    constexpr int GRP = 256 / NOUT;
    constexpr int PR  = ROWS / GRP;
    int col = tid % NOUT, rg = tid / NOUT;
    float acc[PR];
#pragma unroll
    for (int r = 0; r < PR; ++r) acc[r] = 0.f;
    for (int k = 0; k < 128; ++k) {
        float w = W[k * NOUT + col];
#pragma unroll
        for (int r = 0; r < PR; ++r) acc[r] += xs[rg + r * GRP][k] * w;
    }
#pragma unroll
    for (int r = 0; r < PR; ++r) {
        int row = row0 + rg + r * GRP;
        if (row < N) Hout[(size_t)row * NOUT + col] = __float2half(acc[r]);
    }
}

// ---- per (node, head): al_src/al_dst from fp16 h
template<int C>
__global__ void k_al(const __half* __restrict__ Hm, const float* __restrict__ as_,
                     const float* __restrict__ ad_, float* __restrict__ als,
                     float* __restrict__ ald, int N) {
    int idx = blockIdx.x * 256 + threadIdx.x;
    int n = idx >> 2, h = idx & 3;
    if (n >= N) return;
    constexpr int CH = C / 4;
    const __half2* h2p = (const __half2*)(Hm + (size_t)n * C + h * CH);
    float a = 0.f, b = 0.f;
#pragma unroll
    for (int c = 0; c < CH / 2; ++c) {
        float2 v = __half22float2(h2p[c]);
        a += v.x * as_[h * CH + 2 * c] + v.y * as_[h * CH + 2 * c + 1];
        b += v.x * ad_[h * CH + 2 * c] + v.y * ad_[h * CH + 2 * c + 1];
    }
    als[n * 4 + h] = a;
    ald[n * 4 + h] = b;
}

// ---- wave-per-node: alpha_csr = exp(leaky(als[src]+ald[n]+ale_e[eid])), rden/selfa
__global__ __launch_bounds__(256) void k_alpha_node(const __half* __restrict__ ale_e,
                                                    __half* __restrict__ alpha_csr,
                                                    const int2* __restrict__ csr_se,
                                                    const float* __restrict__ als,
                                                    const float* __restrict__ ald,
                                                    const int* __restrict__ offsets,
                                                    float* __restrict__ rden,
                                                    float* __restrict__ selfa, int N) {
    int n = (blockIdx.x * 256 + threadIdx.x) >> 6;
    int lane = threadIdx.x & 63;
    if (n >= N) return;
    int j = lane >> 2, h = lane & 3;   // 16 edges x 4 heads per iteration
    int s0 = offsets[n], s1 = offsets[n + 1];
    float aldn = ald[n * 4 + h];
    float den = 0.f, asum = 0.f;
    for (int base = s0; base < s1; base += 16) {
        int s = base + j;
        if (s < s1) {
            int2 se = csr_se[s];
            float ale = __half2float(ale_e[(size_t)se.y * 4 + h]);
            float v = als[se.x * 4 + h] + aldn + ale;
            v = (v > 0.f) ? v : NEG_SLOPE * v;
            float e = __expf(v);
            alpha_csr[s * 4 + h] = __float2half(e);
            den += e; asum += ale;
        }
    }
    den  += __shfl_xor(den, 4);  den  += __shfl_xor(den, 8);
    den  += __shfl_xor(den, 16); den  += __shfl_xor(den, 32);
    asum += __shfl_xor(asum, 4);  asum += __shfl_xor(asum, 8);
    asum += __shfl_xor(asum, 16); asum += __shfl_xor(asum, 32);
    if (j == 0) {
        float rdeg = 1.f / fmaxf((float)(s1 - s0), 1.f);
        float v = als[n * 4 + h] + aldn + asum * rdeg;
        v = (v > 0.f) ? v : NEG_SLOPE * v;
        float es = __expf(v);
        selfa[n * 4 + h] = es;
        rden[n * 4 + h] = 1.f / (den + es + 1e-16f);
    }
}

// ---- layer-1 aggregation: gather-FMA, wave-per-node, unroll x4, predicated tail
__global__ __launch_bounds__(256) void k_aggf128(const __half* __restrict__ h16,
                                                 const __half* __restrict__ alpha16,
                                                 const float* __restrict__ rden,
                                                 const float* __restrict__ selfa,
                                                 const int* __restrict__ offsets,
                                                 const int2* __restrict__ csr_se,
                                                 const float* __restrict__ bias,
                                                 float* __restrict__ Out, int N) {
    int n = (blockIdx.x * 256 + threadIdx.x) >> 6;
    int lane = threadIdx.x & 63;
    if (n >= N) return;
    int hd = lane >> 4;                 // head of channels 2l, 2l+1
    int s0 = offsets[n], s1 = offsets[n + 1];
    const __half2* H2 = (const __half2*)h16;
    float acc0 = 0.f, acc1 = 0.f;
    int e1 = s1 - 1;
    for (int s = s0; s < s1; s += 4) {
        int sA = s;
        int sB = min(s + 1, e1), sC = min(s + 2, e1), sD = min(s + 3, e1);
        int srcA = csr_se[sA].x, srcB = csr_se[sB].x;
        int srcC = csr_se[sC].x, srcD = csr_se[sD].x;
        float aA = __half2float(alpha16[sA * 4 + hd]);
        float aB = (s + 1 <= e1) ? __half2float(alpha16[sB * 4 + hd]) : 0.f;
        float aC = (s + 2 <= e1) ? __half2float(alpha16[sC * 4 + hd]) : 0.f;
        float aD = (s + 3 <= e1) ? __half2float(alpha16[sD * 4 + hd]) : 0.f;
        __half2 hA = H2[(size_t)srcA * 64 + lane];
        __half2 hB = H2[(size_t)srcB * 64 + lane];
        __half2 hC = H2[(size_t)srcC * 64 + lane];
        __half2 hD = H2[(size_t)srcD * 64 + lane];
        float2 fA = __half22float2(hA), fB = __half22float2(hB);
        float2 fC = __half22float2(hC), fD = __half22float2(hD);
        acc0 = fmaf(aA, fA.x, acc0); acc1 = fmaf(aA, fA.y, acc1);
        acc0 = fmaf(aB, fB.x, acc0); acc1 = fmaf(aB, fB.y, acc1);
        acc0 = fmaf(aC, fC.x, acc0); acc1 = fmaf(aC, fC.y, acc1);
        acc0 = fmaf(aD, fD.x, acc0); acc1 = fmaf(aD, fD.y, acc1);
    }
    float sa = selfa[n * 4 + hd];
    float2 hn = __half22float2(H2[(size_t)n * 64 + lane]);
    acc0 = fmaf(sa, hn.x, acc0);
    acc1 = fmaf(sa, hn.y, acc1);
    float rd = rden[n * 4 + hd];
    float2 bv = ((const float2*)bias)[lane];
    float2 o;
    o.x = fmaxf(fmaf(acc0, rd, bv.x), 0.f);
    o.y = fmaxf(fmaf(acc1, rd, bv.y), 0.f);
    ((float2*)Out)[(size_t)n * 64 + lane] = o;
}

// ---- layer-2 aggregation: 4 edges/iter across the wave, unroll x2
__global__ __launch_bounds__(256) void k_aggf32(const __half* __restrict__ h16,
                                                const __half* __restrict__ alpha16,
                                                const float* __restrict__ rden,
                                                const float* __restrict__ selfa,
                                                const int* __restrict__ offsets,
                                                const int2* __restrict__ csr_se,
                                                const float* __restrict__ bias,
                                                float* __restrict__ Out, int N) {
    int n = (blockIdx.x * 256 + threadIdx.x) >> 6;
    int lane = threadIdx.x & 63;
    if (n >= N) return;
    int j = lane >> 4;                  // edge sub-slot 0..3
    int p = lane & 15;                  // half2 index -> channels 2p,2p+1
    int hd = p >> 2;                    // head
    int s0 = offsets[n], s1 = offsets[n + 1];
    const __half2* H2 = (const __half2*)h16;
    float acc0 = 0.f, acc1 = 0.f;
    int e1 = s1 - 1;
    for (int s = s0 + j; s < s1; s += 8) {
        int sA = s;
        int sB = min(s + 4, e1);
        int srcA = csr_se[sA].x, srcB = csr_se[sB].x;
        float aA = __half2float(alpha16[sA * 4 + hd]);
        float aB = (s + 4 <= e1) ? __half2float(alpha16[sB * 4 + hd]) : 0.f;
        __half2 hA = H2[(size_t)srcA * 16 + p];
        __half2 hB = H2[(size_t)srcB * 16 + p];
        float2 fA = __half22float2(hA), fB = __half22float2(hB);
        acc0 = fmaf(aA, fA.x, acc0); acc1 = fmaf(aA, fA.y, acc1);
        acc0 = fmaf(aB, fB.x, acc0); acc1 = fmaf(aB, fB.y, acc1);
    }
    acc0 += __shfl_xor(acc0, 16); acc0 += __shfl_xor(acc0, 32);
    acc1 += __shfl_xor(acc1, 16); acc1 += __shfl_xor(acc1, 32);
    if (j == 0) {
        float sa = selfa[n * 4 + hd];
        float2 hn = __half22float2(H2[(size_t)n * 16 + p]);
        acc0 = fmaf(sa, hn.x, acc0);
        acc1 = fmaf(sa, hn.y, acc1);
        float rd = rden[n * 4 + hd];
        float2 bv = ((const float2*)bias)[p];
        float2 o;
        o.x = fmaxf(fmaf(acc0, rd, bv.x), 0.f);
        o.y = fmaxf(fmaf(acc1, rd, bv.y), 0.f);
        ((float2*)Out)[(size_t)n * 16 + p] = o;
    }
}

// ---- group boundaries: gstart[g] = lower_bound(batch, g), g in [0,64]
__global__ void k_gbound(const int* __restrict__ batch, int* __restrict__ gstart, int N, int G) {
    int g = threadIdx.x;
    if (g > G) return;
    int lo = 0, hi = N;
    while (lo < hi) {
        int mid = (lo + hi) >> 1;
        if (batch[mid] < g) lo = mid + 1; else hi = mid;
    }
    gstart[g] = lo;
}

// ---- atomic-free mean pool
__global__ __launch_bounds__(256) void k_pool_grp(const float* __restrict__ out2,
                                                  const int* __restrict__ gstart,
                                                  float* __restrict__ pooled, int G) {
    __shared__ float red[8][32];
    int g = blockIdx.x;
    int t = threadIdx.x, c = t & 31, r = t >> 5;
    int s0 = gstart[g], s1 = gstart[g + 1];
    float acc = 0.f;
    for (int n = s0 + r; n < s1; n += 8) acc += out2[(size_t)n * 32 + c];
    red[r][c] = acc;
    __syncthreads();
    if (r == 0) {
        float s = red[0][c];
#pragma unroll
        for (int i = 1; i < 8; ++i) s += red[i][c];
        pooled[g * 32 + c] = s;
    }
}

// ---- final FC
__global__ void k_final(const float* __restrict__ pooled, const int* __restrict__ gstart,
                        const float* __restrict__ Wfc, const float* __restrict__ bfc,
                        float* __restrict__ out) {
    int t = threadIdx.x;
    if (t >= 640) return;
    int g = t / 10, cls = t % 10;
    float rc = 1.f / fmaxf((float)(gstart[g + 1] - gstart[g]), 1.f);
    float acc = bfc[cls];
    for (int c = 0; c < 32; ++c) acc += pooled[g * 32 + c] * rc * Wfc[c * 10 + cls];
    out[g * 10 + cls] = acc;
}

extern "C" void kernel_launch(void* const* d_in, const int* in_sizes, int n_in,
                              void* d_out, int out_size, void* d_ws, size_t ws_size,
                              hipStream_t stream) {
    const float* x    = (const float*)d_in[0];
    const int*   ei   = (const int*)  d_in[1];
    const float* ea   = (const float*)d_in[2];
    const int*   batch= (const int*)  d_in[3];
    const float* W1   = (const float*)d_in[4];
    const float* as1  = (const float*)d_in[5];
    const float* ad1  = (const float*)d_in[6];
    const float* We1  = (const float*)d_in[7];
    const float* ae1  = (const float*)d_in[8];
    const float* b1   = (const float*)d_in[9];
    const float* W2   = (const float*)d_in[10];
    const float* as2  = (const float*)d_in[11];
    const float* ad2  = (const float*)d_in[12];
    const float* We2  = (const float*)d_in[13];
    const float* ae2  = (const float*)d_in[14];
    const float* b2   = (const float*)d_in[15];
    const float* Wfc  = (const float*)d_in[16];
    const float* bfc  = (const float*)d_in[17];
    float* out = (float*)d_out;

    const int N  = in_sizes[3];       // 50000
    const int E  = in_sizes[1] / 2;   // 1600000
    const int G  = 64;
    const int NB = (N + 63) >> 6;     // 782 buckets of 64 nodes

    char* w = (char*)d_ws;
    size_t off = 0;
    auto alloc = [&](size_t bytes) -> void* {
        void* p = w + off;
        off = (off + bytes + 255) & ~(size_t)255;
        return p;
    };
    int*    bcnt     = (int*)   alloc((size_t)NBMAX * 4);
    int*    bprefix  = (int*)   alloc((size_t)(NBMAX + 1) * 4);
    int*    bcursor  = (int*)   alloc((size_t)NBMAX * 4);
    int*    offsets  = (int*)   alloc((size_t)(N + 1) * 4);
    int2*   binned   = (int2*)  alloc((size_t)E * 8);
    int2*   csr_se   = (int2*)  alloc((size_t)E * 8);
    __half* ale1_e   = (__half*)alloc((size_t)E * 4 * 2);   // edge order
    __half* ale2_e   = (__half*)alloc((size_t)E * 4 * 2);   // edge order
    __half* alpha_csr= (__half*)alloc((size_t)E * 4 * 2);   // csr order (per layer, reused)
    float*  Mbuf     = (float*) alloc(128 * 4);
    __half* h16      = (__half*)alloc((size_t)N * 128 * 2); // h1 fp16; reused as h2
    float*  out1     = (float*) alloc((size_t)N * 128 * 4); // reused as out2
    float*  als      = (float*) alloc((size_t)N * 4 * 4);
    float*  ald      = (float*) alloc((size_t)N * 4 * 4);
    float*  rden     = (float*) alloc((size_t)N * 4 * 4);
    float*  selfa    = (float*) alloc((size_t)N * 4 * 4);
    int*    gstart   = (int*)   alloc((G + 1) * 4);
    float*  pooled   = (float*) alloc(G * 32 * 4);
    float*  out2 = out1;

    const int eb  = (E + 255) / 256;
    const int nb4 = (N + 3) / 4;

    hipMemsetAsync(bcnt, 0, (size_t)NBMAX * 4, stream);

    k_prep<<<1, 128, 0, stream>>>(We1, ae1, We2, ae2, Mbuf);
    k_bhist<<<128, 256, 0, stream>>>(ei, bcnt, E, NB);
    k_bscan<<<1, 1024, 0, stream>>>(bcnt, bprefix, bcursor, NB);
    k_bin<<<(E + BIN_CHUNK - 1) / BIN_CHUNK, 256, 0, stream>>>(ei, bcursor, binned, E, NB);
    k_csr<<<NB, 256, 0, stream>>>(binned, bprefix, offsets, csr_se, N, E, NB);
    k_ale_lin<<<eb, 256, 0, stream>>>(ea, Mbuf, ale1_e, ale2_e, E);
    k_gbound<<<1, 128, 0, stream>>>(batch, gstart, N, G);

    // ---------- layer 1 ----------
    k_gemm<128, 16><<<(N + 15) / 16, 256, 0, stream>>>(x, W1, h16, N);
    k_al<128><<<(N * 4 + 255) / 256, 256, 0, stream>>>(h16, as1, ad1, als, ald, N);
    k_alpha_node<<<nb4, 256, 0, stream>>>(ale1_e, alpha_csr, csr_se, als, ald, offsets, rden, selfa, N);
    k_aggf128<<<nb4, 256, 0, stream>>>(h16, alpha_csr, rden, selfa, offsets, csr_se, b1, out1, N);

    // ---------- layer 2 ----------
    k_gemm<32, 64><<<(N + 63) / 64, 256, 0, stream>>>(out1, W2, h16, N);
    k_al<32><<<(N * 4 + 255) / 256, 256, 0, stream>>>(h16, as2, ad2, als, ald, N);
    k_alpha_node<<<nb4, 256, 0, stream>>>(ale2_e, alpha_csr, csr_se, als, ald, offsets, rden, selfa, N);
    k_aggf32<<<nb4, 256, 0, stream>>>(h16, alpha_csr, rden, selfa, offsets, csr_se, b2, out2, N);

    // ---------- pool + fc ----------
    k_pool_grp<<<G, 256, 0, stream>>>(out2, gstart, pooled, G);
    k_final<<<1, 640, 0, stream>>>(pooled, gstart, Wfc, bfc, out);
}